// Round 2
// 299.170 us; speedup vs baseline: 1.0468x; 1.0468x over previous
//
#include <hip/hip_runtime.h>

// LightGCN encoder: out = (A·e0 + A²·e0 + A³·e0)/3, A = 600K-edge COO.
// R7 vs R6: fix compile error only — __builtin_nontemporal_store needs a
// native vector type, not HIP's float4 class; use ext_vector_type(4) float.
// R6 changes (unbenched until now):
//  (a) spmm gather restructured: 16 lanes/row, uint4 (16B/lane) gathers.
//      A 64-lane wave owns 4 rows; 4-deep edge unroll keeps 4KB of random
//      gather traffic in flight -> better latency hiding, half the loads.
//  (b) final fp32 acc stores nontemporal (write-once, never re-read).
//  (c) conv_k + hist_rank_k fused into one partitioned launch.
constexpr int USER_NUM = 100000;
constexpr int ITEM_NUM = 50000;
constexpr int N_NODES  = USER_NUM + ITEM_NUM;
constexpr int EMB      = 128;
constexpr int N_EDGES  = 600000;
constexpr int SCAN_BS  = 1024;

constexpr int CVT_N      = N_NODES * EMB / 8;           // 2.4M uint4 outputs
constexpr int CVT_BLOCKS = CVT_N / 256;                 // 9375 exact
constexpr int EBLOCKS    = (N_EDGES + 255) / 256;       // 2344

typedef float vf4 __attribute__((ext_vector_type(4))); // native, for NT stores

__device__ __forceinline__ float bf2f(unsigned u16) {
    return __uint_as_float(u16 << 16);
}
__device__ __forceinline__ unsigned f2bf(float f) {   // RTNE
    unsigned u = __float_as_uint(f);
    u += 0x7fffu + ((u >> 16) & 1u);
    return u >> 16;
}
__device__ __forceinline__ void fmadd_bf8(float* s, float v, uint4 g) {
    s[0] += v * bf2f(g.x & 0xffffu);
    s[1] += v * bf2f(g.x >> 16);
    s[2] += v * bf2f(g.y & 0xffffu);
    s[3] += v * bf2f(g.y >> 16);
    s[4] += v * bf2f(g.z & 0xffffu);
    s[5] += v * bf2f(g.z >> 16);
    s[6] += v * bf2f(g.w & 0xffffu);
    s[7] += v * bf2f(g.w >> 16);
}

// ---------------- fused: e0 fp32 -> packed bf16  |  histogram+rank --------
// blocks [0, CVT_BLOCKS): conversion (8 floats/thread; USER_NUM*EMB/4 even,
// so both float4s of a thread come from the same table).
// blocks [CVT_BLOCKS, CVT_BLOCKS+EBLOCKS): per-edge histogram + rank.
__global__ __launch_bounds__(256) void conv_hist_k(
        const float4* __restrict__ ue, const float4* __restrict__ ie,
        uint4* __restrict__ xb, const int* __restrict__ er,
        int* __restrict__ cnt, int* __restrict__ rank) {
    int b = blockIdx.x;
    if (b < CVT_BLOCKS) {
        int i = b * 256 + threadIdx.x;              // < CVT_N exactly
        const int u4 = USER_NUM * EMB / 4;          // 3.2M float4s
        int f = 2 * i;
        float4 a, c;
        if (f < u4) { a = ue[f]; c = ue[f + 1]; }
        else        { a = ie[f - u4]; c = ie[f + 1 - u4]; }
        uint4 o;
        o.x = f2bf(a.x) | (f2bf(a.y) << 16);
        o.y = f2bf(a.z) | (f2bf(a.w) << 16);
        o.z = f2bf(c.x) | (f2bf(c.y) << 16);
        o.w = f2bf(c.z) | (f2bf(c.w) << 16);
        xb[i] = o;
    } else {
        int e = (b - CVT_BLOCKS) * 256 + threadIdx.x;
        if (e < N_EDGES) rank[e] = atomicAdd(&cnt[er[e]], 1);
    }
}

// fused scan: per-block LDS scan + atomic global base -> rowinfo (start,cnt).
// Segments are disjoint but not row-ordered across blocks (irrelevant).
__global__ __launch_bounds__(SCAN_BS) void scan_fused_k(
        const int* __restrict__ cnt, int* __restrict__ gcount,
        int2* __restrict__ rowinfo) {
    __shared__ int sh[SCAN_BS];
    __shared__ int sbase;
    int i = blockIdx.x * SCAN_BS + threadIdx.x;
    int v = (i < N_NODES) ? cnt[i] : 0;
    sh[threadIdx.x] = v;
    __syncthreads();
    for (int off = 1; off < SCAN_BS; off <<= 1) {
        int t = (threadIdx.x >= off) ? sh[threadIdx.x - off] : 0;
        __syncthreads();
        sh[threadIdx.x] += t;
        __syncthreads();
    }
    if (threadIdx.x == SCAN_BS - 1)
        sbase = atomicAdd(gcount, sh[SCAN_BS - 1]);
    __syncthreads();
    if (i < N_NODES)
        rowinfo[i] = make_int2(sbase + sh[threadIdx.x] - v, v);
}

// atomic-free scatter: position = rowstart + precomputed rank
__global__ void scatter_k(const int* __restrict__ er, const int* __restrict__ ec,
                          const float* __restrict__ ev, const int* __restrict__ rank,
                          const int2* __restrict__ rowinfo, int2* __restrict__ edges) {
    int e = blockIdx.x * 256 + threadIdx.x;
    if (e >= N_EDGES) return;
    int p = rowinfo[er[e]].x + rank[e];
    edges[p] = make_int2(ec[e], __float_as_int(ev[e]));
}

// ---------------- gather SpMM (bf16 x, fp32 accumulate) ----------------
// 16 lanes per row, uint4 (8 bf16) per lane. 16 rows per 256-block,
// 4 rows per 64-lane wave. 4-deep edge unroll -> 4KB gather in flight/wave.
// MODE 0/1: out = bf16 layer buffer.
// MODE 2:   s = A*e2; read e1 (b0) and e2 (x) linearly; acc = (e1+e2+s)/3 fp32.
template <int MODE>
__global__ __launch_bounds__(256) void spmm_gather_bf(
        const uint4* __restrict__ x, const int2* __restrict__ rowinfo,
        const int2* __restrict__ edges, uint4* __restrict__ out,
        const uint4* __restrict__ b0, float* __restrict__ acc) {
    int row  = blockIdx.x * 16 + (threadIdx.x >> 4);  // 16 rows / 256-block
    int lane = threadIdx.x & 15;                      // 8 bf16 (16B) of EMB
    int2 ri = rowinfo[row];
    int e0 = ri.x, eend = ri.x + ri.y;
    float s[8] = {0.f, 0.f, 0.f, 0.f, 0.f, 0.f, 0.f, 0.f};
    for (int base = e0; base < eend; base += 4) {
        int i1 = (base + 1 < eend) ? base + 1 : eend - 1;
        int i2 = (base + 2 < eend) ? base + 2 : eend - 1;
        int i3 = (base + 3 < eend) ? base + 3 : eend - 1;
        int2 p0 = edges[base], p1 = edges[i1], p2 = edges[i2], p3 = edges[i3];
        float v0 = __int_as_float(p0.y);
        float v1 = (base + 1 < eend) ? __int_as_float(p1.y) : 0.f;
        float v2 = (base + 2 < eend) ? __int_as_float(p2.y) : 0.f;
        float v3 = (base + 3 < eend) ? __int_as_float(p3.y) : 0.f;
        // 4 independent 256B gathers in flight (16B per lane)
        uint4 g0 = x[(size_t)p0.x * 16 + lane];
        uint4 g1 = x[(size_t)p1.x * 16 + lane];
        uint4 g2 = x[(size_t)p2.x * 16 + lane];
        uint4 g3 = x[(size_t)p3.x * 16 + lane];
        fmadd_bf8(s, v0, g0);
        fmadd_bf8(s, v1, g1);
        fmadd_bf8(s, v2, g2);
        fmadd_bf8(s, v3, g3);
    }
    size_t o = (size_t)row * 16 + lane;
    if (MODE < 2) {
        uint4 w;
        w.x = f2bf(s[0]) | (f2bf(s[1]) << 16);
        w.y = f2bf(s[2]) | (f2bf(s[3]) << 16);
        w.z = f2bf(s[4]) | (f2bf(s[5]) << 16);
        w.w = f2bf(s[6]) | (f2bf(s[7]) << 16);
        out[o] = w;
    } else {
        uint4 a0 = b0[o];           // e1, linear bf16
        uint4 a1 = x[o];            // e2, linear bf16 (same buffer we gather)
        const float k = 1.0f / 3.0f;
        vf4 r0, r1;
        r0.x = (s[0] + bf2f(a0.x & 0xffffu) + bf2f(a1.x & 0xffffu)) * k;
        r0.y = (s[1] + bf2f(a0.x >> 16)     + bf2f(a1.x >> 16))     * k;
        r0.z = (s[2] + bf2f(a0.y & 0xffffu) + bf2f(a1.y & 0xffffu)) * k;
        r0.w = (s[3] + bf2f(a0.y >> 16)     + bf2f(a1.y >> 16))     * k;
        r1.x = (s[4] + bf2f(a0.z & 0xffffu) + bf2f(a1.z & 0xffffu)) * k;
        r1.y = (s[5] + bf2f(a0.z >> 16)     + bf2f(a1.z >> 16))     * k;
        r1.z = (s[6] + bf2f(a0.w & 0xffffu) + bf2f(a1.w & 0xffffu)) * k;
        r1.w = (s[7] + bf2f(a0.w >> 16)     + bf2f(a1.w >> 16))     * k;
        vf4* dst = reinterpret_cast<vf4*>(acc) + (size_t)row * 32 + (size_t)lane * 2;
        __builtin_nontemporal_store(r0, dst);
        __builtin_nontemporal_store(r1, dst + 1);
    }
}

// ---------------- fallback (atomic path, used only if ws too small) ----
__global__ void spmm_first_at(const float* __restrict__ ue, const float* __restrict__ ie,
                              const float* __restrict__ ev, const int* __restrict__ er,
                              const int* __restrict__ ec, float* __restrict__ out) {
    int tid = blockIdx.x * blockDim.x + threadIdx.x;
    int edge = tid >> 5;
    if (edge >= N_EDGES) return;
    int lane = tid & 31;
    int row = er[edge]; int col = ec[edge]; float v = ev[edge];
    const float* x = (col < USER_NUM) ? (ue + (size_t)col * EMB)
                                      : (ie + (size_t)(col - USER_NUM) * EMB);
    float4 g = ((const float4*)x)[lane];
    float* o = out + (size_t)row * EMB + lane * 4;
    atomicAdd(o + 0, v * g.x); atomicAdd(o + 1, v * g.y);
    atomicAdd(o + 2, v * g.z); atomicAdd(o + 3, v * g.w);
}
__global__ void spmm_at(const float* __restrict__ x, const float* __restrict__ ev,
                        const int* __restrict__ er, const int* __restrict__ ec,
                        float* __restrict__ out) {
    int tid = blockIdx.x * blockDim.x + threadIdx.x;
    int edge = tid >> 5;
    if (edge >= N_EDGES) return;
    int lane = tid & 31;
    int row = er[edge]; int col = ec[edge]; float v = ev[edge];
    float4 g = ((const float4*)(x + (size_t)col * EMB))[lane];
    float* o = out + (size_t)row * EMB + lane * 4;
    atomicAdd(o + 0, v * g.x); atomicAdd(o + 1, v * g.y);
    atomicAdd(o + 2, v * g.z); atomicAdd(o + 3, v * g.w);
}
__global__ void acc_add(float* __restrict__ acc, const float* __restrict__ cur,
                        float scale, int n4) {
    int i = blockIdx.x * blockDim.x + threadIdx.x;
    if (i >= n4) return;
    float4 a = ((const float4*)acc)[i];
    float4 c = ((const float4*)cur)[i];
    a.x = (a.x + c.x) * scale; a.y = (a.y + c.y) * scale;
    a.z = (a.z + c.z) * scale; a.w = (a.w + c.w) * scale;
    ((float4*)acc)[i] = a;
}

extern "C" void kernel_launch(void* const* d_in, const int* in_sizes, int n_in,
                              void* d_out, int out_size, void* d_ws, size_t ws_size,
                              hipStream_t stream) {
    const float* ue = (const float*)d_in[0];
    const float* ie = (const float*)d_in[1];
    const float* ev = (const float*)d_in[2];
    const int*   er = (const int*)d_in[3];
    const int*   ec = (const int*)d_in[4];
    float* acc = (float*)d_out;

    size_t nnodes16 = (size_t)N_NODES * 16;           // uint4 per row = 16

    // main-path workspace (bf16 buffers)
    uint4* x0   = (uint4*)d_ws;                       // e0 bf16, 38.4 MB
    uint4* e1b  = x0 + nnodes16;                      // e1 bf16
    uint4* e2b  = e1b + nnodes16;                     // e2 bf16
    int*   cnt  = (int*)(e2b + nnodes16);             // N_NODES
    int*   gcount = cnt + N_NODES;                    // 1 (zeroed with cnt)
    int2*  rowinfo = (int2*)(gcount + 1);             // N_NODES (start,count)
    int*   rank = (int*)(rowinfo + N_NODES);          // N_EDGES
    int2*  edges = (int2*)(rank + N_EDGES);           // N_EDGES packed (c,v)
    size_t needed = (char*)(edges + N_EDGES) - (char*)d_ws;

    const int BLOCK = 256;
    const int nscan = (N_NODES + SCAN_BS - 1) / SCAN_BS;   // 147

    if (ws_size >= needed) {
        // CSR count buffer must be zero before conv_hist_k's hist half
        (void)hipMemsetAsync(cnt, 0, ((size_t)N_NODES + 1) * sizeof(int), stream);
        // fused conversion + histogram/rank
        conv_hist_k<<<CVT_BLOCKS + EBLOCKS, BLOCK, 0, stream>>>(
            (const float4*)ue, (const float4*)ie, x0, er, cnt, rank);
        scan_fused_k<<<nscan, SCAN_BS, 0, stream>>>(cnt, gcount, rowinfo);
        scatter_k<<<EBLOCKS, BLOCK, 0, stream>>>(er, ec, ev, rank, rowinfo, edges);

        // 3 gather layers (16 rows per block)
        const int gblocks = N_NODES / 16;             // 9375, exact
        spmm_gather_bf<0><<<gblocks, BLOCK, 0, stream>>>(
            x0, rowinfo, edges, e1b, nullptr, nullptr);
        spmm_gather_bf<1><<<gblocks, BLOCK, 0, stream>>>(
            e1b, rowinfo, edges, e2b, nullptr, nullptr);
        spmm_gather_bf<2><<<gblocks, BLOCK, 0, stream>>>(
            e2b, rowinfo, edges, nullptr, e1b, acc);
    } else {
        // fallback: atomic path (fp32 buffers at d_ws)
        size_t nfloats = (size_t)N_NODES * EMB;
        float* buf0 = (float*)d_ws;
        float* buf1 = buf0 + nfloats;
        const int spmm_blocks = (N_EDGES * 32) / BLOCK;
        const int n4 = (int)(nfloats / 4);
        const int add_blocks = (n4 + BLOCK - 1) / BLOCK;
        (void)hipMemsetAsync(acc, 0, nfloats * sizeof(float), stream);
        (void)hipMemsetAsync(buf0, 0, nfloats * sizeof(float), stream);
        spmm_first_at<<<spmm_blocks, BLOCK, 0, stream>>>(ue, ie, ev, er, ec, buf0);
        acc_add<<<add_blocks, BLOCK, 0, stream>>>(acc, buf0, 1.0f, n4);
        (void)hipMemsetAsync(buf1, 0, nfloats * sizeof(float), stream);
        spmm_at<<<spmm_blocks, BLOCK, 0, stream>>>(buf0, ev, er, ec, buf1);
        acc_add<<<add_blocks, BLOCK, 0, stream>>>(acc, buf1, 1.0f, n4);
        (void)hipMemsetAsync(buf0, 0, nfloats * sizeof(float), stream);
        spmm_at<<<spmm_blocks, BLOCK, 0, stream>>>(buf1, ev, er, ec, buf0);
        acc_add<<<add_blocks, BLOCK, 0, stream>>>(acc, buf0, 1.0f / 3.0f, n4);
    }
}

// Round 3
// 298.259 us; speedup vs baseline: 1.0500x; 1.0031x over previous
//
#include <hip/hip_runtime.h>

// LightGCN encoder: out = (A·e0 + A²·e0 + A³·e0)/3, A = 600K-edge COO.
// R8 vs R7:
//  (a) conv kernel ELIMINATED: layer-1 spmm gathers fp32 directly from
//      ue/ie (32B/lane, 512B/row) and emits e1 in bf16. Saves ~100MB of
//      conv traffic + one dispatch; fp32 inputs are L3-resident in-pass.
//  (b) hist un-fused (R6 fusion was a 71µs regression: atomic partition
//      stalls mixed with streaming partition; standalone both were <47µs).
//  (c) keep R6: 16 lanes/row uint4 gathers for layers 2/3, NT final stores.
constexpr int USER_NUM = 100000;
constexpr int ITEM_NUM = 50000;
constexpr int N_NODES  = USER_NUM + ITEM_NUM;
constexpr int EMB      = 128;
constexpr int N_EDGES  = 600000;
constexpr int SCAN_BS  = 1024;

constexpr int EBLOCKS = (N_EDGES + 255) / 256;       // 2344

typedef float vf4 __attribute__((ext_vector_type(4))); // native, for NT stores

__device__ __forceinline__ float bf2f(unsigned u16) {
    return __uint_as_float(u16 << 16);
}
__device__ __forceinline__ unsigned f2bf(float f) {   // RTNE
    unsigned u = __float_as_uint(f);
    u += 0x7fffu + ((u >> 16) & 1u);
    return u >> 16;
}
__device__ __forceinline__ void fmadd_bf8(float* s, float v, uint4 g) {
    s[0] += v * bf2f(g.x & 0xffffu);
    s[1] += v * bf2f(g.x >> 16);
    s[2] += v * bf2f(g.y & 0xffffu);
    s[3] += v * bf2f(g.y >> 16);
    s[4] += v * bf2f(g.z & 0xffffu);
    s[5] += v * bf2f(g.z >> 16);
    s[6] += v * bf2f(g.w & 0xffffu);
    s[7] += v * bf2f(g.w >> 16);
}

// ---------------- CSR build ----------------
// histogram + per-edge rank in one pass
__global__ void hist_rank_k(const int* __restrict__ er, int* __restrict__ cnt,
                            int* __restrict__ rank) {
    int e = blockIdx.x * 256 + threadIdx.x;
    if (e < N_EDGES) rank[e] = atomicAdd(&cnt[er[e]], 1);
}

// fused scan: per-block LDS scan + atomic global base -> rowinfo (start,cnt).
// Segments are disjoint but not row-ordered across blocks (irrelevant).
__global__ __launch_bounds__(SCAN_BS) void scan_fused_k(
        const int* __restrict__ cnt, int* __restrict__ gcount,
        int2* __restrict__ rowinfo) {
    __shared__ int sh[SCAN_BS];
    __shared__ int sbase;
    int i = blockIdx.x * SCAN_BS + threadIdx.x;
    int v = (i < N_NODES) ? cnt[i] : 0;
    sh[threadIdx.x] = v;
    __syncthreads();
    for (int off = 1; off < SCAN_BS; off <<= 1) {
        int t = (threadIdx.x >= off) ? sh[threadIdx.x - off] : 0;
        __syncthreads();
        sh[threadIdx.x] += t;
        __syncthreads();
    }
    if (threadIdx.x == SCAN_BS - 1)
        sbase = atomicAdd(gcount, sh[SCAN_BS - 1]);
    __syncthreads();
    if (i < N_NODES)
        rowinfo[i] = make_int2(sbase + sh[threadIdx.x] - v, v);
}

// atomic-free scatter: position = rowstart + precomputed rank
__global__ void scatter_k(const int* __restrict__ er, const int* __restrict__ ec,
                          const float* __restrict__ ev, const int* __restrict__ rank,
                          const int2* __restrict__ rowinfo, int2* __restrict__ edges) {
    int e = blockIdx.x * 256 + threadIdx.x;
    if (e >= N_EDGES) return;
    int p = rowinfo[er[e]].x + rank[e];
    edges[p] = make_int2(ec[e], __float_as_int(ev[e]));
}

// ---------------- layer-1 SpMM: fp32 gather from ue/ie, bf16 out --------
// 16 lanes/row, 32B/lane (two vf4). 4-deep edge unroll -> 8KB/wave in flight.
__global__ __launch_bounds__(256) void spmm_l1_fp32(
        const float* __restrict__ ue, const float* __restrict__ ie,
        const int2* __restrict__ rowinfo, const int2* __restrict__ edges,
        uint4* __restrict__ out) {
    int row  = blockIdx.x * 16 + (threadIdx.x >> 4);
    int lane = threadIdx.x & 15;
    int2 ri = rowinfo[row];
    int e0 = ri.x, eend = ri.x + ri.y;
    float s[8] = {0.f, 0.f, 0.f, 0.f, 0.f, 0.f, 0.f, 0.f};
    for (int base = e0; base < eend; base += 4) {
        int i1 = (base + 1 < eend) ? base + 1 : eend - 1;
        int i2 = (base + 2 < eend) ? base + 2 : eend - 1;
        int i3 = (base + 3 < eend) ? base + 3 : eend - 1;
        int2 p0 = edges[base], p1 = edges[i1], p2 = edges[i2], p3 = edges[i3];
        float v0 = __int_as_float(p0.y);
        float v1 = (base + 1 < eend) ? __int_as_float(p1.y) : 0.f;
        float v2 = (base + 2 < eend) ? __int_as_float(p2.y) : 0.f;
        float v3 = (base + 3 < eend) ? __int_as_float(p3.y) : 0.f;
        // branch-free pointer select (col uniform across the 16-lane group)
        const vf4* s0 = (const vf4*)((p0.x < USER_NUM) ? ue + (size_t)p0.x * EMB
                                     : ie + (size_t)(p0.x - USER_NUM) * EMB);
        const vf4* s1 = (const vf4*)((p1.x < USER_NUM) ? ue + (size_t)p1.x * EMB
                                     : ie + (size_t)(p1.x - USER_NUM) * EMB);
        const vf4* s2 = (const vf4*)((p2.x < USER_NUM) ? ue + (size_t)p2.x * EMB
                                     : ie + (size_t)(p2.x - USER_NUM) * EMB);
        const vf4* s3 = (const vf4*)((p3.x < USER_NUM) ? ue + (size_t)p3.x * EMB
                                     : ie + (size_t)(p3.x - USER_NUM) * EMB);
        // 8 independent loads (32B/lane x 4 edges) in flight
        vf4 a0 = s0[lane * 2], b0 = s0[lane * 2 + 1];
        vf4 a1 = s1[lane * 2], b1 = s1[lane * 2 + 1];
        vf4 a2 = s2[lane * 2], b2 = s2[lane * 2 + 1];
        vf4 a3 = s3[lane * 2], b3 = s3[lane * 2 + 1];
        s[0] += v0 * a0.x; s[1] += v0 * a0.y; s[2] += v0 * a0.z; s[3] += v0 * a0.w;
        s[4] += v0 * b0.x; s[5] += v0 * b0.y; s[6] += v0 * b0.z; s[7] += v0 * b0.w;
        s[0] += v1 * a1.x; s[1] += v1 * a1.y; s[2] += v1 * a1.z; s[3] += v1 * a1.w;
        s[4] += v1 * b1.x; s[5] += v1 * b1.y; s[6] += v1 * b1.z; s[7] += v1 * b1.w;
        s[0] += v2 * a2.x; s[1] += v2 * a2.y; s[2] += v2 * a2.z; s[3] += v2 * a2.w;
        s[4] += v2 * b2.x; s[5] += v2 * b2.y; s[6] += v2 * b2.z; s[7] += v2 * b2.w;
        s[0] += v3 * a3.x; s[1] += v3 * a3.y; s[2] += v3 * a3.z; s[3] += v3 * a3.w;
        s[4] += v3 * b3.x; s[5] += v3 * b3.y; s[6] += v3 * b3.z; s[7] += v3 * b3.w;
    }
    uint4 w;
    w.x = f2bf(s[0]) | (f2bf(s[1]) << 16);
    w.y = f2bf(s[2]) | (f2bf(s[3]) << 16);
    w.z = f2bf(s[4]) | (f2bf(s[5]) << 16);
    w.w = f2bf(s[6]) | (f2bf(s[7]) << 16);
    out[(size_t)row * 16 + lane] = w;
}

// ---------------- gather SpMM layers 2/3 (bf16 x, fp32 accumulate) -------
// 16 lanes/row, uint4 (8 bf16) per lane. 4-deep unroll -> 4KB/wave in flight.
// MODE 1: out = bf16 layer buffer.
// MODE 2: s = A*e2; read e1 (b0) and e2 (x) linearly; acc = (e1+e2+s)/3 fp32.
template <int MODE>
__global__ __launch_bounds__(256) void spmm_gather_bf(
        const uint4* __restrict__ x, const int2* __restrict__ rowinfo,
        const int2* __restrict__ edges, uint4* __restrict__ out,
        const uint4* __restrict__ b0, float* __restrict__ acc) {
    int row  = blockIdx.x * 16 + (threadIdx.x >> 4);
    int lane = threadIdx.x & 15;
    int2 ri = rowinfo[row];
    int e0 = ri.x, eend = ri.x + ri.y;
    float s[8] = {0.f, 0.f, 0.f, 0.f, 0.f, 0.f, 0.f, 0.f};
    for (int base = e0; base < eend; base += 4) {
        int i1 = (base + 1 < eend) ? base + 1 : eend - 1;
        int i2 = (base + 2 < eend) ? base + 2 : eend - 1;
        int i3 = (base + 3 < eend) ? base + 3 : eend - 1;
        int2 p0 = edges[base], p1 = edges[i1], p2 = edges[i2], p3 = edges[i3];
        float v0 = __int_as_float(p0.y);
        float v1 = (base + 1 < eend) ? __int_as_float(p1.y) : 0.f;
        float v2 = (base + 2 < eend) ? __int_as_float(p2.y) : 0.f;
        float v3 = (base + 3 < eend) ? __int_as_float(p3.y) : 0.f;
        // 4 independent 256B gathers in flight (16B per lane)
        uint4 g0 = x[(size_t)p0.x * 16 + lane];
        uint4 g1 = x[(size_t)p1.x * 16 + lane];
        uint4 g2 = x[(size_t)p2.x * 16 + lane];
        uint4 g3 = x[(size_t)p3.x * 16 + lane];
        fmadd_bf8(s, v0, g0);
        fmadd_bf8(s, v1, g1);
        fmadd_bf8(s, v2, g2);
        fmadd_bf8(s, v3, g3);
    }
    size_t o = (size_t)row * 16 + lane;
    if (MODE < 2) {
        uint4 w;
        w.x = f2bf(s[0]) | (f2bf(s[1]) << 16);
        w.y = f2bf(s[2]) | (f2bf(s[3]) << 16);
        w.z = f2bf(s[4]) | (f2bf(s[5]) << 16);
        w.w = f2bf(s[6]) | (f2bf(s[7]) << 16);
        out[o] = w;
    } else {
        uint4 a0 = b0[o];           // e1, linear bf16
        uint4 a1 = x[o];            // e2, linear bf16 (same buffer we gather)
        const float k = 1.0f / 3.0f;
        vf4 r0, r1;
        r0.x = (s[0] + bf2f(a0.x & 0xffffu) + bf2f(a1.x & 0xffffu)) * k;
        r0.y = (s[1] + bf2f(a0.x >> 16)     + bf2f(a1.x >> 16))     * k;
        r0.z = (s[2] + bf2f(a0.y & 0xffffu) + bf2f(a1.y & 0xffffu)) * k;
        r0.w = (s[3] + bf2f(a0.y >> 16)     + bf2f(a1.y >> 16))     * k;
        r1.x = (s[4] + bf2f(a0.z & 0xffffu) + bf2f(a1.z & 0xffffu)) * k;
        r1.y = (s[5] + bf2f(a0.z >> 16)     + bf2f(a1.z >> 16))     * k;
        r1.z = (s[6] + bf2f(a0.w & 0xffffu) + bf2f(a1.w & 0xffffu)) * k;
        r1.w = (s[7] + bf2f(a0.w >> 16)     + bf2f(a1.w >> 16))     * k;
        vf4* dst = reinterpret_cast<vf4*>(acc) + (size_t)row * 32 + (size_t)lane * 2;
        __builtin_nontemporal_store(r0, dst);
        __builtin_nontemporal_store(r1, dst + 1);
    }
}

// ---------------- fallback (atomic path, used only if ws too small) ----
__global__ void spmm_first_at(const float* __restrict__ ue, const float* __restrict__ ie,
                              const float* __restrict__ ev, const int* __restrict__ er,
                              const int* __restrict__ ec, float* __restrict__ out) {
    int tid = blockIdx.x * blockDim.x + threadIdx.x;
    int edge = tid >> 5;
    if (edge >= N_EDGES) return;
    int lane = tid & 31;
    int row = er[edge]; int col = ec[edge]; float v = ev[edge];
    const float* x = (col < USER_NUM) ? (ue + (size_t)col * EMB)
                                      : (ie + (size_t)(col - USER_NUM) * EMB);
    float4 g = ((const float4*)x)[lane];
    float* o = out + (size_t)row * EMB + lane * 4;
    atomicAdd(o + 0, v * g.x); atomicAdd(o + 1, v * g.y);
    atomicAdd(o + 2, v * g.z); atomicAdd(o + 3, v * g.w);
}
__global__ void spmm_at(const float* __restrict__ x, const float* __restrict__ ev,
                        const int* __restrict__ er, const int* __restrict__ ec,
                        float* __restrict__ out) {
    int tid = blockIdx.x * blockDim.x + threadIdx.x;
    int edge = tid >> 5;
    if (edge >= N_EDGES) return;
    int lane = tid & 31;
    int row = er[edge]; int col = ec[edge]; float v = ev[edge];
    float4 g = ((const float4*)(x + (size_t)col * EMB))[lane];
    float* o = out + (size_t)row * EMB + lane * 4;
    atomicAdd(o + 0, v * g.x); atomicAdd(o + 1, v * g.y);
    atomicAdd(o + 2, v * g.z); atomicAdd(o + 3, v * g.w);
}
__global__ void acc_add(float* __restrict__ acc, const float* __restrict__ cur,
                        float scale, int n4) {
    int i = blockIdx.x * blockDim.x + threadIdx.x;
    if (i >= n4) return;
    float4 a = ((const float4*)acc)[i];
    float4 c = ((const float4*)cur)[i];
    a.x = (a.x + c.x) * scale; a.y = (a.y + c.y) * scale;
    a.z = (a.z + c.z) * scale; a.w = (a.w + c.w) * scale;
    ((float4*)acc)[i] = a;
}

extern "C" void kernel_launch(void* const* d_in, const int* in_sizes, int n_in,
                              void* d_out, int out_size, void* d_ws, size_t ws_size,
                              hipStream_t stream) {
    const float* ue = (const float*)d_in[0];
    const float* ie = (const float*)d_in[1];
    const float* ev = (const float*)d_in[2];
    const int*   er = (const int*)d_in[3];
    const int*   ec = (const int*)d_in[4];
    float* acc = (float*)d_out;

    size_t nnodes16 = (size_t)N_NODES * 16;           // uint4 per row = 16

    // main-path workspace (bf16 buffers)
    uint4* e1b  = (uint4*)d_ws;                       // e1 bf16, 38.4 MB
    uint4* e2b  = e1b + nnodes16;                     // e2 bf16
    int*   cnt  = (int*)(e2b + nnodes16);             // N_NODES
    int*   gcount = cnt + N_NODES;                    // 1 (zeroed with cnt)
    int2*  rowinfo = (int2*)(gcount + 1);             // N_NODES (start,count)
    int*   rank = (int*)(rowinfo + N_NODES);          // N_EDGES
    int2*  edges = (int2*)(rank + N_EDGES);           // N_EDGES packed (c,v)
    size_t needed = (char*)(edges + N_EDGES) - (char*)d_ws;

    const int BLOCK = 256;
    const int nscan = (N_NODES + SCAN_BS - 1) / SCAN_BS;   // 147

    if (ws_size >= needed) {
        // CSR build
        (void)hipMemsetAsync(cnt, 0, ((size_t)N_NODES + 1) * sizeof(int), stream);
        hist_rank_k<<<EBLOCKS, BLOCK, 0, stream>>>(er, cnt, rank);
        scan_fused_k<<<nscan, SCAN_BS, 0, stream>>>(cnt, gcount, rowinfo);
        scatter_k<<<EBLOCKS, BLOCK, 0, stream>>>(er, ec, ev, rank, rowinfo, edges);

        // 3 gather layers (16 rows per block)
        const int gblocks = N_NODES / 16;             // 9375, exact
        spmm_l1_fp32<<<gblocks, BLOCK, 0, stream>>>(
            ue, ie, rowinfo, edges, e1b);
        spmm_gather_bf<1><<<gblocks, BLOCK, 0, stream>>>(
            e1b, rowinfo, edges, e2b, nullptr, nullptr);
        spmm_gather_bf<2><<<gblocks, BLOCK, 0, stream>>>(
            e2b, rowinfo, edges, nullptr, e1b, acc);
    } else {
        // fallback: atomic path (fp32 buffers at d_ws)
        size_t nfloats = (size_t)N_NODES * EMB;
        float* buf0 = (float*)d_ws;
        float* buf1 = buf0 + nfloats;
        const int spmm_blocks = (N_EDGES * 32) / BLOCK;
        const int n4 = (int)(nfloats / 4);
        const int add_blocks = (n4 + BLOCK - 1) / BLOCK;
        (void)hipMemsetAsync(acc, 0, nfloats * sizeof(float), stream);
        (void)hipMemsetAsync(buf0, 0, nfloats * sizeof(float), stream);
        spmm_first_at<<<spmm_blocks, BLOCK, 0, stream>>>(ue, ie, ev, er, ec, buf0);
        acc_add<<<add_blocks, BLOCK, 0, stream>>>(acc, buf0, 1.0f, n4);
        (void)hipMemsetAsync(buf1, 0, nfloats * sizeof(float), stream);
        spmm_at<<<spmm_blocks, BLOCK, 0, stream>>>(buf0, ev, er, ec, buf1);
        acc_add<<<add_blocks, BLOCK, 0, stream>>>(acc, buf1, 1.0f, n4);
        (void)hipMemsetAsync(buf0, 0, nfloats * sizeof(float), stream);
        spmm_at<<<spmm_blocks, BLOCK, 0, stream>>>(buf1, ev, er, ec, buf0);
        acc_add<<<add_blocks, BLOCK, 0, stream>>>(acc, buf0, 1.0f / 3.0f, n4);
    }
}

// Round 4
// 294.437 us; speedup vs baseline: 1.0636x; 1.0130x over previous
//
#include <hip/hip_runtime.h>

// LightGCN encoder: out = (A·e0 + A²·e0 + A³·e0)/3, A = 600K-edge COO.
// R9 vs R8:
//  (a) L1 gathers bf16 again (256B/row not 512B): measured gather ceiling
//      ~5.5 TB/s delivered regardless of tier -> bytes/edge is the lever.
//  (b) e0->bf16 conversion fused into scatter_k (both NON-atomic; the R6
//      71µs fusion failure was conv+ATOMIC-hist co-scheduling).
//  (c) keep: 16 lanes/row uint4 gathers (raised delivered BW 4.0->5.5TB/s),
//      atomic-free scatter via precomputed rank, NT final stores.
constexpr int USER_NUM = 100000;
constexpr int ITEM_NUM = 50000;
constexpr int N_NODES  = USER_NUM + ITEM_NUM;
constexpr int EMB      = 128;
constexpr int N_EDGES  = 600000;
constexpr int SCAN_BS  = 1024;

constexpr int EBLOCKS    = (N_EDGES + 255) / 256;       // 2344
constexpr int CVT_N      = N_NODES * EMB / 8;           // 2.4M uint4 outputs
constexpr int CVT_BLOCKS = CVT_N / 256;                 // 9375 exact

typedef float vf4 __attribute__((ext_vector_type(4))); // native, for NT stores

__device__ __forceinline__ float bf2f(unsigned u16) {
    return __uint_as_float(u16 << 16);
}
__device__ __forceinline__ unsigned f2bf(float f) {   // RTNE
    unsigned u = __float_as_uint(f);
    u += 0x7fffu + ((u >> 16) & 1u);
    return u >> 16;
}
__device__ __forceinline__ void fmadd_bf8(float* s, float v, uint4 g) {
    s[0] += v * bf2f(g.x & 0xffffu);
    s[1] += v * bf2f(g.x >> 16);
    s[2] += v * bf2f(g.y & 0xffffu);
    s[3] += v * bf2f(g.y >> 16);
    s[4] += v * bf2f(g.z & 0xffffu);
    s[5] += v * bf2f(g.z >> 16);
    s[6] += v * bf2f(g.w & 0xffffu);
    s[7] += v * bf2f(g.w >> 16);
}

// ---------------- CSR build ----------------
// histogram + per-edge rank in one pass (atomic; kept ALONE on purpose)
__global__ void hist_rank_k(const int* __restrict__ er, int* __restrict__ cnt,
                            int* __restrict__ rank) {
    int e = blockIdx.x * 256 + threadIdx.x;
    if (e < N_EDGES) rank[e] = atomicAdd(&cnt[er[e]], 1);
}

// fused scan: per-block LDS scan + atomic global base -> rowinfo (start,cnt).
__global__ __launch_bounds__(SCAN_BS) void scan_fused_k(
        const int* __restrict__ cnt, int* __restrict__ gcount,
        int2* __restrict__ rowinfo) {
    __shared__ int sh[SCAN_BS];
    __shared__ int sbase;
    int i = blockIdx.x * SCAN_BS + threadIdx.x;
    int v = (i < N_NODES) ? cnt[i] : 0;
    sh[threadIdx.x] = v;
    __syncthreads();
    for (int off = 1; off < SCAN_BS; off <<= 1) {
        int t = (threadIdx.x >= off) ? sh[threadIdx.x - off] : 0;
        __syncthreads();
        sh[threadIdx.x] += t;
        __syncthreads();
    }
    if (threadIdx.x == SCAN_BS - 1)
        sbase = atomicAdd(gcount, sh[SCAN_BS - 1]);
    __syncthreads();
    if (i < N_NODES)
        rowinfo[i] = make_int2(sbase + sh[threadIdx.x] - v, v);
}

// ---------------- fused: edge scatter | e0 fp32 -> packed bf16 ----------
// Both partitions are non-atomic. blocks [0, EBLOCKS): atomic-free scatter
// (pos = rowstart + rank). blocks [EBLOCKS, EBLOCKS+CVT_BLOCKS): conversion
// (8 floats/thread; USER_NUM*EMB/4 even so both float4s are same-table).
__global__ __launch_bounds__(256) void scatter_conv_k(
        const int* __restrict__ er, const int* __restrict__ ec,
        const float* __restrict__ ev, const int* __restrict__ rank,
        const int2* __restrict__ rowinfo, int2* __restrict__ edges,
        const float4* __restrict__ ue, const float4* __restrict__ ie,
        uint4* __restrict__ xb) {
    int b = blockIdx.x;
    if (b < EBLOCKS) {
        int e = b * 256 + threadIdx.x;
        if (e >= N_EDGES) return;
        int p = rowinfo[er[e]].x + rank[e];
        edges[p] = make_int2(ec[e], __float_as_int(ev[e]));
    } else {
        int i = (b - EBLOCKS) * 256 + threadIdx.x;  // < CVT_N exactly
        const int u4 = USER_NUM * EMB / 4;          // 3.2M float4s
        int f = 2 * i;
        float4 a, c;
        if (f < u4) { a = ue[f]; c = ue[f + 1]; }
        else        { a = ie[f - u4]; c = ie[f + 1 - u4]; }
        uint4 o;
        o.x = f2bf(a.x) | (f2bf(a.y) << 16);
        o.y = f2bf(a.z) | (f2bf(a.w) << 16);
        o.z = f2bf(c.x) | (f2bf(c.y) << 16);
        o.w = f2bf(c.z) | (f2bf(c.w) << 16);
        xb[i] = o;
    }
}

// ---------------- gather SpMM (bf16 x, fp32 accumulate) ----------------
// 16 lanes/row, uint4 (8 bf16) per lane. 16 rows per 256-block,
// 4 rows per 64-lane wave. 4-deep edge unroll -> 4KB/wave gather in flight.
// MODE 0/1: out = bf16 layer buffer.
// MODE 2:   s = A*e2; read e1 (b0) and e2 (x) linearly; acc = (e1+e2+s)/3 fp32.
template <int MODE>
__global__ __launch_bounds__(256) void spmm_gather_bf(
        const uint4* __restrict__ x, const int2* __restrict__ rowinfo,
        const int2* __restrict__ edges, uint4* __restrict__ out,
        const uint4* __restrict__ b0, float* __restrict__ acc) {
    int row  = blockIdx.x * 16 + (threadIdx.x >> 4);
    int lane = threadIdx.x & 15;
    int2 ri = rowinfo[row];
    int e0 = ri.x, eend = ri.x + ri.y;
    float s[8] = {0.f, 0.f, 0.f, 0.f, 0.f, 0.f, 0.f, 0.f};
    for (int base = e0; base < eend; base += 4) {
        int i1 = (base + 1 < eend) ? base + 1 : eend - 1;
        int i2 = (base + 2 < eend) ? base + 2 : eend - 1;
        int i3 = (base + 3 < eend) ? base + 3 : eend - 1;
        int2 p0 = edges[base], p1 = edges[i1], p2 = edges[i2], p3 = edges[i3];
        float v0 = __int_as_float(p0.y);
        float v1 = (base + 1 < eend) ? __int_as_float(p1.y) : 0.f;
        float v2 = (base + 2 < eend) ? __int_as_float(p2.y) : 0.f;
        float v3 = (base + 3 < eend) ? __int_as_float(p3.y) : 0.f;
        // 4 independent 256B gathers in flight (16B per lane)
        uint4 g0 = x[(size_t)p0.x * 16 + lane];
        uint4 g1 = x[(size_t)p1.x * 16 + lane];
        uint4 g2 = x[(size_t)p2.x * 16 + lane];
        uint4 g3 = x[(size_t)p3.x * 16 + lane];
        fmadd_bf8(s, v0, g0);
        fmadd_bf8(s, v1, g1);
        fmadd_bf8(s, v2, g2);
        fmadd_bf8(s, v3, g3);
    }
    size_t o = (size_t)row * 16 + lane;
    if (MODE < 2) {
        uint4 w;
        w.x = f2bf(s[0]) | (f2bf(s[1]) << 16);
        w.y = f2bf(s[2]) | (f2bf(s[3]) << 16);
        w.z = f2bf(s[4]) | (f2bf(s[5]) << 16);
        w.w = f2bf(s[6]) | (f2bf(s[7]) << 16);
        out[o] = w;
    } else {
        uint4 a0 = b0[o];           // e1, linear bf16
        uint4 a1 = x[o];            // e2, linear bf16 (same buffer we gather)
        const float k = 1.0f / 3.0f;
        vf4 r0, r1;
        r0.x = (s[0] + bf2f(a0.x & 0xffffu) + bf2f(a1.x & 0xffffu)) * k;
        r0.y = (s[1] + bf2f(a0.x >> 16)     + bf2f(a1.x >> 16))     * k;
        r0.z = (s[2] + bf2f(a0.y & 0xffffu) + bf2f(a1.y & 0xffffu)) * k;
        r0.w = (s[3] + bf2f(a0.y >> 16)     + bf2f(a1.y >> 16))     * k;
        r1.x = (s[4] + bf2f(a0.z & 0xffffu) + bf2f(a1.z & 0xffffu)) * k;
        r1.y = (s[5] + bf2f(a0.z >> 16)     + bf2f(a1.z >> 16))     * k;
        r1.z = (s[6] + bf2f(a0.w & 0xffffu) + bf2f(a1.w & 0xffffu)) * k;
        r1.w = (s[7] + bf2f(a0.w >> 16)     + bf2f(a1.w >> 16))     * k;
        vf4* dst = reinterpret_cast<vf4*>(acc) + (size_t)row * 32 + (size_t)lane * 2;
        __builtin_nontemporal_store(r0, dst);
        __builtin_nontemporal_store(r1, dst + 1);
    }
}

// ---------------- fallback (atomic path, used only if ws too small) ----
__global__ void spmm_first_at(const float* __restrict__ ue, const float* __restrict__ ie,
                              const float* __restrict__ ev, const int* __restrict__ er,
                              const int* __restrict__ ec, float* __restrict__ out) {
    int tid = blockIdx.x * blockDim.x + threadIdx.x;
    int edge = tid >> 5;
    if (edge >= N_EDGES) return;
    int lane = tid & 31;
    int row = er[edge]; int col = ec[edge]; float v = ev[edge];
    const float* x = (col < USER_NUM) ? (ue + (size_t)col * EMB)
                                      : (ie + (size_t)(col - USER_NUM) * EMB);
    float4 g = ((const float4*)x)[lane];
    float* o = out + (size_t)row * EMB + lane * 4;
    atomicAdd(o + 0, v * g.x); atomicAdd(o + 1, v * g.y);
    atomicAdd(o + 2, v * g.z); atomicAdd(o + 3, v * g.w);
}
__global__ void spmm_at(const float* __restrict__ x, const float* __restrict__ ev,
                        const int* __restrict__ er, const int* __restrict__ ec,
                        float* __restrict__ out) {
    int tid = blockIdx.x * blockDim.x + threadIdx.x;
    int edge = tid >> 5;
    if (edge >= N_EDGES) return;
    int lane = tid & 31;
    int row = er[edge]; int col = ec[edge]; float v = ev[edge];
    float4 g = ((const float4*)(x + (size_t)col * EMB))[lane];
    float* o = out + (size_t)row * EMB + lane * 4;
    atomicAdd(o + 0, v * g.x); atomicAdd(o + 1, v * g.y);
    atomicAdd(o + 2, v * g.z); atomicAdd(o + 3, v * g.w);
}
__global__ void acc_add(float* __restrict__ acc, const float* __restrict__ cur,
                        float scale, int n4) {
    int i = blockIdx.x * blockDim.x + threadIdx.x;
    if (i >= n4) return;
    float4 a = ((const float4*)acc)[i];
    float4 c = ((const float4*)cur)[i];
    a.x = (a.x + c.x) * scale; a.y = (a.y + c.y) * scale;
    a.z = (a.z + c.z) * scale; a.w = (a.w + c.w) * scale;
    ((float4*)acc)[i] = a;
}

extern "C" void kernel_launch(void* const* d_in, const int* in_sizes, int n_in,
                              void* d_out, int out_size, void* d_ws, size_t ws_size,
                              hipStream_t stream) {
    const float* ue = (const float*)d_in[0];
    const float* ie = (const float*)d_in[1];
    const float* ev = (const float*)d_in[2];
    const int*   er = (const int*)d_in[3];
    const int*   ec = (const int*)d_in[4];
    float* acc = (float*)d_out;

    size_t nnodes16 = (size_t)N_NODES * 16;           // uint4 per row = 16

    // main-path workspace (bf16 buffers)
    uint4* x0   = (uint4*)d_ws;                       // e0 bf16, 38.4 MB
    uint4* e1b  = x0 + nnodes16;                      // e1 bf16
    uint4* e2b  = e1b + nnodes16;                     // e2 bf16
    int*   cnt  = (int*)(e2b + nnodes16);             // N_NODES
    int*   gcount = cnt + N_NODES;                    // 1 (zeroed with cnt)
    int2*  rowinfo = (int2*)(gcount + 1);             // N_NODES (start,count)
    int*   rank = (int*)(rowinfo + N_NODES);          // N_EDGES
    int2*  edges = (int2*)(rank + N_EDGES);           // N_EDGES packed (c,v)
    size_t needed = (char*)(edges + N_EDGES) - (char*)d_ws;

    const int BLOCK = 256;
    const int nscan = (N_NODES + SCAN_BS - 1) / SCAN_BS;   // 147

    if (ws_size >= needed) {
        // CSR build (hist kept alone: atomic waves must not co-schedule
        // with streaming partitions — R6 evidence)
        (void)hipMemsetAsync(cnt, 0, ((size_t)N_NODES + 1) * sizeof(int), stream);
        hist_rank_k<<<EBLOCKS, BLOCK, 0, stream>>>(er, cnt, rank);
        scan_fused_k<<<nscan, SCAN_BS, 0, stream>>>(cnt, gcount, rowinfo);
        // scatter + e0->bf16 conversion fused (both non-atomic)
        scatter_conv_k<<<EBLOCKS + CVT_BLOCKS, BLOCK, 0, stream>>>(
            er, ec, ev, rank, rowinfo, edges,
            (const float4*)ue, (const float4*)ie, x0);

        // 3 gather layers (16 rows per block)
        const int gblocks = N_NODES / 16;             // 9375, exact
        spmm_gather_bf<0><<<gblocks, BLOCK, 0, stream>>>(
            x0, rowinfo, edges, e1b, nullptr, nullptr);
        spmm_gather_bf<1><<<gblocks, BLOCK, 0, stream>>>(
            e1b, rowinfo, edges, e2b, nullptr, nullptr);
        spmm_gather_bf<2><<<gblocks, BLOCK, 0, stream>>>(
            e2b, rowinfo, edges, nullptr, e1b, acc);
    } else {
        // fallback: atomic path (fp32 buffers at d_ws)
        size_t nfloats = (size_t)N_NODES * EMB;
        float* buf0 = (float*)d_ws;
        float* buf1 = buf0 + nfloats;
        const int spmm_blocks = (N_EDGES * 32) / BLOCK;
        const int n4 = (int)(nfloats / 4);
        const int add_blocks = (n4 + BLOCK - 1) / BLOCK;
        (void)hipMemsetAsync(acc, 0, nfloats * sizeof(float), stream);
        (void)hipMemsetAsync(buf0, 0, nfloats * sizeof(float), stream);
        spmm_first_at<<<spmm_blocks, BLOCK, 0, stream>>>(ue, ie, ev, er, ec, buf0);
        acc_add<<<add_blocks, BLOCK, 0, stream>>>(acc, buf0, 1.0f, n4);
        (void)hipMemsetAsync(buf1, 0, nfloats * sizeof(float), stream);
        spmm_at<<<spmm_blocks, BLOCK, 0, stream>>>(buf0, ev, er, ec, buf1);
        acc_add<<<add_blocks, BLOCK, 0, stream>>>(acc, buf1, 1.0f, n4);
        (void)hipMemsetAsync(buf0, 0, nfloats * sizeof(float), stream);
        spmm_at<<<spmm_blocks, BLOCK, 0, stream>>>(buf1, ev, er, ec, buf0);
        acc_add<<<add_blocks, BLOCK, 0, stream>>>(acc, buf0, 1.0f / 3.0f, n4);
    }
}